// Round 6
// baseline (225.500 us; speedup 1.0000x reference)
//
#include <hip/hip_runtime.h>
#include <hip/hip_bf16.h>
#include <math.h>

#define NQ 13294
#define NV 13294
#define M_ROWS (2*NQ)     // 26588
#define MP 26624          // padded row count

typedef __attribute__((ext_vector_type(8))) short bf16x8;
typedef __attribute__((ext_vector_type(4))) float f32x4;

__device__ __forceinline__ float4 ld4(const float* p){ return *(const float4*)p; }
__device__ __forceinline__ float bfu_lo(unsigned int u){ return __uint_as_float(u << 16); }
__device__ __forceinline__ float bfu_hi(unsigned int u){ return __uint_as_float(u & 0xffff0000u); }
__device__ __forceinline__ unsigned short f2bf(float f){
  unsigned int u = __float_as_uint(f);
  u += 0x7fffu + ((u >> 16) & 1u);   // RNE
  return (unsigned short)(u >> 16);
}
__device__ __forceinline__ unsigned int pk2(float a, float b){
  return (unsigned int)f2bf(a) | ((unsigned int)f2bf(b) << 16);
}

// ---- prep: transpose 5 weights f32 [K][N] -> bf16 [N][K] (K=256) ----
__global__ __launch_bounds__(256) void prep_w(
    const float* __restrict__ wv, const float* __restrict__ wo,
    const float* __restrict__ wa, const float* __restrict__ wu,
    const float* __restrict__ wf, unsigned short* __restrict__ wt)
{
  int t = blockIdx.x * 256 + threadIdx.x;
  if (t >= 294912) return;
  const float* src; int Nn; int base;
  if      (t < 65536)  { src = wv; Nn = 256; base = 0; }
  else if (t < 131072) { src = wo; Nn = 256; base = 65536; }
  else if (t < 163840) { src = wa; Nn = 128; base = 131072; }
  else if (t < 229376) { src = wu; Nn = 256; base = 163840; }
  else                 { src = wf; Nn = 256; base = 229376; }
  const int local = t - base;
  const int n = local >> 8, k = local & 255;
  wt[t] = f2bf(src[k * Nn + n]);
}

// ---- 64x64-tile bf16 MFMA GEMM, BK=64, double-buffered LDS ----
// Grid: x = column-block (FAST, 4..6 values -> A-band re-reads are L2/L3-adjacent),
//       y = row-band (416).
// A_MODE: 0 = bf16 A; 1 = f32 A (inline convert); 2 = f32 A + f32 A2 (sum, convert)
// C = A @ Bt^T + bias [+ RES];  Bt: [N][256] bf16 pre-transposed weights.
template<int A_MODE, bool OUT_BF16, bool ADD_RES>
__global__ __launch_bounds__(256) void gemm64(
    const void* __restrict__ Av, const float* __restrict__ A2,
    const unsigned short* __restrict__ Bt,
    const float* __restrict__ biasA, const float* __restrict__ biasB,
    const float* __restrict__ RES, void* __restrict__ Cv, int N)
{
  __shared__ unsigned short As[2][64*64];   // [row][k] bf16, XOR-swizzled 128B rows
  __shared__ unsigned short Bs[2][64*64];

  const int tid  = threadIdx.x;
  const int bcol = blockIdx.x * 64;   // fast dim: column
  const int brow = blockIdx.y * 64;   // slow dim: rows
  const int wid  = tid >> 6, lane = tid & 63;
  const int wr   = wid >> 1, wc = wid & 1;
  const int fr   = lane & 15, fg = lane >> 4;

  const int srow = tid >> 3;         // 0..31
  const int slot = (tid & 7) << 4;   // byte col 0..112
  const int ke0  = (tid & 7) << 3;   // element col 0..56

  f32x4 acc[2][2];
  #pragma unroll
  for (int m = 0; m < 2; ++m)
    #pragma unroll
    for (int n = 0; n < 2; ++n)
      acc[m][n] = (f32x4){0.f, 0.f, 0.f, 0.f};

  uint4 a_st[2], b_st[2];

  auto stage = [&](int k0) {
    #pragma unroll
    for (int c = 0; c < 2; ++c) {
      const int row = c * 32 + srow;
      const int ke  = k0 + ke0;
      b_st[c] = *(const uint4*)(Bt + (size_t)(bcol + row) * 256 + ke);
      if (A_MODE == 0) {
        a_st[c] = *(const uint4*)((const unsigned short*)Av + (size_t)(brow + row) * 256 + ke);
      } else {
        const int gr = brow + row;
        float4 f0 = make_float4(0.f,0.f,0.f,0.f), f1 = f0;
        if (gr < M_ROWS) {
          f0 = ld4((const float*)Av + (size_t)gr * 256 + ke);
          f1 = ld4((const float*)Av + (size_t)gr * 256 + ke + 4);
          if (A_MODE == 2) {
            float4 g0 = ld4(A2 + (size_t)gr * 256 + ke);
            float4 g1 = ld4(A2 + (size_t)gr * 256 + ke + 4);
            f0.x += g0.x; f0.y += g0.y; f0.z += g0.z; f0.w += g0.w;
            f1.x += g1.x; f1.y += g1.y; f1.z += g1.z; f1.w += g1.w;
          }
        }
        a_st[c].x = pk2(f0.x, f0.y); a_st[c].y = pk2(f0.z, f0.w);
        a_st[c].z = pk2(f1.x, f1.y); a_st[c].w = pk2(f1.z, f1.w);
      }
    }
  };

  auto write_lds = [&](int buf) {
    #pragma unroll
    for (int c = 0; c < 2; ++c) {
      const int row = c * 32 + srow;
      const int sw  = slot ^ ((row & 7) << 4);
      *(uint4*)((char*)&As[buf][0] + row * 128 + sw) = a_st[c];
      *(uint4*)((char*)&Bs[buf][0] + row * 128 + sw) = b_st[c];
    }
  };

  auto compute = [&](int buf) {
    #pragma unroll
    for (int kk = 0; kk < 2; ++kk) {
      const int kb = kk * 64 + fg * 16;
      bf16x8 af[2], bf[2];
      #pragma unroll
      for (int m = 0; m < 2; ++m) {
        const int r = wr * 32 + m * 16 + fr;
        af[m] = *(const bf16x8*)((const char*)&As[buf][0] + r * 128 + (kb ^ ((r & 7) << 4)));
      }
      #pragma unroll
      for (int n = 0; n < 2; ++n) {
        const int r = wc * 32 + n * 16 + fr;
        bf[n] = *(const bf16x8*)((const char*)&Bs[buf][0] + r * 128 + (kb ^ ((r & 7) << 4)));
      }
      #pragma unroll
      for (int m = 0; m < 2; ++m)
        #pragma unroll
        for (int n = 0; n < 2; ++n)
          acc[m][n] = __builtin_amdgcn_mfma_f32_16x16x32_bf16(af[m], bf[n], acc[m][n], 0, 0, 0);
    }
  };

  stage(0);
  write_lds(0);
  #pragma unroll
  for (int t = 0; t < 4; ++t) {
    if (t < 3) stage((t + 1) * 64);     // global loads in flight during compute
    __syncthreads();                    // buf[t&1] ready for all waves
    compute(t & 1);
    if (t < 3) write_lds((t + 1) & 1);  // other buffer; next barrier protects readers
  }

  // epilogue
  const int cn0 = bcol + wc * 32 + fr;
  const int cn1 = cn0 + 16;
  const float bn0 = (cn0 < 256) ? biasA[cn0] : biasB[cn0 - 256];
  const float bn1 = (cn1 < 256) ? biasA[cn1] : biasB[cn1 - 256];
  #pragma unroll
  for (int m = 0; m < 2; ++m) {
    #pragma unroll
    for (int j = 0; j < 4; ++j) {
      const int r = brow + wr * 32 + m * 16 + fg * 4 + j;
      if (r >= M_ROWS) continue;
      float v0 = acc[m][0][j] + bn0;
      float v1 = acc[m][1][j] + bn1;
      if (ADD_RES) {
        v0 += RES[(size_t)r * 256 + cn0];
        v1 += RES[(size_t)r * 256 + cn1];
      }
      if (OUT_BF16) {
        ((unsigned short*)Cv)[(size_t)r * N + cn0] = f2bf(v0);
        ((unsigned short*)Cv)[(size_t)r * N + cn1] = f2bf(v1);
      } else {
        ((float*)Cv)[(size_t)r * N + cn0] = v0;
        ((float*)Cv)[(size_t)r * N + cn1] = v1;
      }
    }
  }
}

// ---- deformable sampling: 8 queries/block, 4 lanes per (q,h), 8 ch/lane ----
// oa: fused (M,384) f32: [0:256) = offsets, [256:384) = attn logits
__global__ __launch_bounds__(256) void msda4(
    const unsigned short* __restrict__ v, const float* __restrict__ oa,
    const float* __restrict__ ref, unsigned short* __restrict__ attout)
{
  constexpr int LW[4] = {100, 50, 25, 13};
  constexpr int LS[4] = {0, 10000, 12500, 13125};

  __shared__ int4   sidx[8][8][16];   // [qi][h][p^pmask] corner BYTE offsets
  __shared__ float4 swt [8][8][16];   // premultiplied weights

  const int nwg = (M_ROWS + 7) / 8;   // 3324
  const int qq = nwg >> 3, rr = nwg & 7;
  const int xcd = blockIdx.x & 7, sub = blockIdx.x >> 3;
  const int wg = (xcd < rr ? xcd * (qq + 1) : rr * (qq + 1) + (xcd - rr) * qq) + sub;

  const int tid = threadIdx.x;
  const int qi  = tid >> 5;          // query in block 0..7
  const int h   = (tid >> 2) & 7;    // head
  const int lq  = tid & 3;           // level (phase1) / channel-octet (phase2)
  const int bq  = wg * 8 + qi;
  const bool active = bq < M_ROWS;
  const int b = (bq >= NQ) ? 1 : 0;
  const int pmask = (h << 1) | (qi & 1);   // distinct per quad within a wave -> bank spread

  if (active) {
    const int l = lq;
    const int W = LW[l];
    const float fD = (float)W;

    float4 lg4 = ld4(oa + (size_t)bq * 384 + 256 + h * 16 + l * 4);
    float mx = fmaxf(fmaxf(lg4.x, lg4.y), fmaxf(lg4.z, lg4.w));
    mx = fmaxf(mx, __shfl_xor(mx, 1));
    mx = fmaxf(mx, __shfl_xor(mx, 2));
    float e0 = __expf(lg4.x - mx), e1 = __expf(lg4.y - mx);
    float e2 = __expf(lg4.z - mx), e3 = __expf(lg4.w - mx);
    float s = e0 + e1 + e2 + e3;
    s += __shfl_xor(s, 1);
    s += __shfl_xor(s, 2);
    const float inv = 1.f / s;
    const float ee[4] = {e0 * inv, e1 * inv, e2 * inv, e3 * inv};

    const float rx = ref[(size_t)bq * 8 + l * 2];
    const float ry = ref[(size_t)bq * 8 + l * 2 + 1];
    float4 o1 = ld4(oa + (size_t)bq * 384 + h * 32 + l * 8);
    float4 o2 = ld4(oa + (size_t)bq * 384 + h * 32 + l * 8 + 4);
    const float oxy[8] = {o1.x, o1.y, o1.z, o1.w, o2.x, o2.y, o2.z, o2.w};
    const int baseb = (LS[l] * 256 + h * 32) * 2;   // byte offset into v

    #pragma unroll
    for (int j = 0; j < 4; ++j) {
      const float x = (rx + oxy[2*j]   / fD) * fD - 0.5f;
      const float y = (ry + oxy[2*j+1] / fD) * fD - 0.5f;
      const float x0f = floorf(x), y0f = floorf(y);
      const float lx = x - x0f, ly = y - y0f;
      const int x0 = (int)x0f, y0 = (int)y0f;
      const int x1 = x0 + 1,  y1 = y0 + 1;
      const int cx0 = min(max(x0, 0), W - 1), cx1 = min(max(x1, 0), W - 1);
      const int cy0 = min(max(y0, 0), W - 1), cy1 = min(max(y1, 0), W - 1);
      const float f00 = (x0 >= 0 && x0 < W && y0 >= 0 && y0 < W) ? 1.f : 0.f;
      const float f10 = (x1 >= 0 && x1 < W && y0 >= 0 && y0 < W) ? 1.f : 0.f;
      const float f01 = (x0 >= 0 && x0 < W && y1 >= 0 && y1 < W) ? 1.f : 0.f;
      const float f11 = (x1 >= 0 && x1 < W && y1 >= 0 && y1 < W) ? 1.f : 0.f;
      const float wt = ee[j];
      const int pi = (l * 4 + j) ^ pmask;
      sidx[qi][h][pi] = make_int4(baseb + (cy0 * W + cx0) * 512,
                                  baseb + (cy0 * W + cx1) * 512,
                                  baseb + (cy1 * W + cx0) * 512,
                                  baseb + (cy1 * W + cx1) * 512);
      swt[qi][h][pi] = make_float4(wt * (1.f - lx) * (1.f - ly) * f00,
                                   wt * lx * (1.f - ly) * f10,
                                   wt * (1.f - lx) * ly * f01,
                                   wt * lx * ly * f11);
    }
  }
  __syncthreads();

  if (active) {
    const char* vb = (const char*)v + (size_t)b * NV * 512 + lq * 16;
    float acc[8] = {0.f, 0.f, 0.f, 0.f, 0.f, 0.f, 0.f, 0.f};
    #pragma unroll
    for (int p = 0; p < 16; ++p) {
      const int4   ix = sidx[qi][h][p ^ pmask];
      const float4 w4 = swt[qi][h][p ^ pmask];
      uint4 c0 = *(const uint4*)(vb + ix.x);
      uint4 c1 = *(const uint4*)(vb + ix.y);
      uint4 c2 = *(const uint4*)(vb + ix.z);
      uint4 c3 = *(const uint4*)(vb + ix.w);
      acc[0] = fmaf(w4.x, bfu_lo(c0.x), acc[0]); acc[1] = fmaf(w4.x, bfu_hi(c0.x), acc[1]);
      acc[2] = fmaf(w4.x, bfu_lo(c0.y), acc[2]); acc[3] = fmaf(w4.x, bfu_hi(c0.y), acc[3]);
      acc[4] = fmaf(w4.x, bfu_lo(c0.z), acc[4]); acc[5] = fmaf(w4.x, bfu_hi(c0.z), acc[5]);
      acc[6] = fmaf(w4.x, bfu_lo(c0.w), acc[6]); acc[7] = fmaf(w4.x, bfu_hi(c0.w), acc[7]);
      acc[0] = fmaf(w4.y, bfu_lo(c1.x), acc[0]); acc[1] = fmaf(w4.y, bfu_hi(c1.x), acc[1]);
      acc[2] = fmaf(w4.y, bfu_lo(c1.y), acc[2]); acc[3] = fmaf(w4.y, bfu_hi(c1.y), acc[3]);
      acc[4] = fmaf(w4.y, bfu_lo(c1.z), acc[4]); acc[5] = fmaf(w4.y, bfu_hi(c1.z), acc[5]);
      acc[6] = fmaf(w4.y, bfu_lo(c1.w), acc[6]); acc[7] = fmaf(w4.y, bfu_hi(c1.w), acc[7]);
      acc[0] = fmaf(w4.z, bfu_lo(c2.x), acc[0]); acc[1] = fmaf(w4.z, bfu_hi(c2.x), acc[1]);
      acc[2] = fmaf(w4.z, bfu_lo(c2.y), acc[2]); acc[3] = fmaf(w4.z, bfu_hi(c2.y), acc[3]);
      acc[4] = fmaf(w4.z, bfu_lo(c2.z), acc[4]); acc[5] = fmaf(w4.z, bfu_hi(c2.z), acc[5]);
      acc[6] = fmaf(w4.z, bfu_lo(c2.w), acc[6]); acc[7] = fmaf(w4.z, bfu_hi(c2.w), acc[7]);
      acc[0] = fmaf(w4.w, bfu_lo(c3.x), acc[0]); acc[1] = fmaf(w4.w, bfu_hi(c3.x), acc[1]);
      acc[2] = fmaf(w4.w, bfu_lo(c3.y), acc[2]); acc[3] = fmaf(w4.w, bfu_hi(c3.y), acc[3]);
      acc[4] = fmaf(w4.w, bfu_lo(c3.z), acc[4]); acc[5] = fmaf(w4.w, bfu_hi(c3.z), acc[5]);
      acc[6] = fmaf(w4.w, bfu_lo(c3.w), acc[6]); acc[7] = fmaf(w4.w, bfu_hi(c3.w), acc[7]);
    }
    uint4 pk;
    pk.x = pk2(acc[0], acc[1]);
    pk.y = pk2(acc[2], acc[3]);
    pk.z = pk2(acc[4], acc[5]);
    pk.w = pk2(acc[6], acc[7]);
    *(uint4*)(attout + (size_t)bq * 256 + h * 32 + lq * 8) = pk;
  }
}

extern "C" void kernel_launch(void* const* d_in, const int* in_sizes, int n_in,
                              void* d_out, int out_size, void* d_ws, size_t ws_size,
                              hipStream_t stream) {
  const float* query  = (const float*)d_in[0];
  const float* value  = (const float*)d_in[2];
  const float* qpos   = (const float*)d_in[3];
  const float* refpts = (const float*)d_in[4];
  const float* W_value = (const float*)d_in[8];
  const float* b_value = (const float*)d_in[9];
  const float* W_off   = (const float*)d_in[10];
  const float* b_off   = (const float*)d_in[11];
  const float* W_attn  = (const float*)d_in[12];
  const float* b_attn  = (const float*)d_in[13];
  const float* W_out   = (const float*)d_in[14];
  const float* b_out   = (const float*)d_in[15];
  const float* W_ffn   = (const float*)d_in[16];
  const float* b_ffn   = (const float*)d_in[17];
  float* out = (float*)d_out;

  // workspace layout (~82.4 MB)
  float* oa_buf = (float*)d_ws;                                   // (MP,384) f32
  unsigned short* vbuf = (unsigned short*)(oa_buf + (size_t)MP * 384); // (MP,256) bf16
  unsigned short* R1   = vbuf + (size_t)MP * 256;                 // attout bf16
  unsigned short* R2   = R1 + (size_t)MP * 256;                   // tmp bf16
  unsigned short* wts  = R2 + (size_t)MP * 256;                   // transposed weights
  unsigned short* wv_t = wts;
  unsigned short* woa_t = wts + 65536;    // [W_off^T ; W_attn^T] rows 0..383
  unsigned short* wu_t = wts + 163840;
  unsigned short* wf_t = wts + 229376;

  const dim3 blk(256);

  prep_w<<<dim3(1152), blk, 0, stream>>>(W_value, W_off, W_attn, W_out, W_ffn, wts);

  // v = value @ W_value + b  -> bf16 (inline f32->bf16 A conversion)
  gemm64<1,true,false><<<dim3(4, 416), blk, 0, stream>>>(
      value, nullptr, wv_t, b_value, b_value, nullptr, vbuf, 256);
  // [off | attn] = (query+qpos) @ [W_off;W_attn] + [b_off;b_attn] -> f32 (M,384)
  gemm64<2,false,false><<<dim3(6, 416), blk, 0, stream>>>(
      query, qpos, woa_t, b_off, b_attn, nullptr, oa_buf, 384);
  // deformable sampling -> attout bf16
  msda4<<<dim3((M_ROWS + 7) / 8), blk, 0, stream>>>(vbuf, oa_buf, refpts, R1);
  // tmp = attout @ W_out + b_out + query (residual) -> bf16
  gemm64<0,true,true><<<dim3(4, 416), blk, 0, stream>>>(
      R1, nullptr, wu_t, b_out, b_out, query, R2, 256);
  // out = tmp @ W_ffn + b_ffn -> f32
  gemm64<0,false,false><<<dim3(4, 416), blk, 0, stream>>>(
      R2, nullptr, wf_t, b_ffn, b_ffn, nullptr, (void*)out, 256);
}

// Round 7
// 185.807 us; speedup vs baseline: 1.2136x; 1.2136x over previous
//
#include <hip/hip_runtime.h>
#include <hip/hip_bf16.h>
#include <math.h>

#define NQ 13294
#define NV 13294
#define M_ROWS (2*NQ)     // 26588
#define MP 26624          // padded row count

typedef __attribute__((ext_vector_type(8))) short bf16x8;
typedef __attribute__((ext_vector_type(4))) float f32x4;

__device__ __forceinline__ float4 ld4(const float* p){ return *(const float4*)p; }
__device__ __forceinline__ float bfu_lo(unsigned int u){ return __uint_as_float(u << 16); }
__device__ __forceinline__ float bfu_hi(unsigned int u){ return __uint_as_float(u & 0xffff0000u); }
__device__ __forceinline__ unsigned short f2bf(float f){
  unsigned int u = __float_as_uint(f);
  u += 0x7fffu + ((u >> 16) & 1u);   // RNE
  return (unsigned short)(u >> 16);
}
__device__ __forceinline__ unsigned int pk2(float a, float b){
  return (unsigned int)f2bf(a) | ((unsigned int)f2bf(b) << 16);
}

// ---- prep: transpose 5 weights f32 [K][N] -> bf16 [N][K] (K=256) ----
__global__ __launch_bounds__(256) void prep_w(
    const float* __restrict__ wv, const float* __restrict__ wo,
    const float* __restrict__ wa, const float* __restrict__ wu,
    const float* __restrict__ wf, unsigned short* __restrict__ wt)
{
  int t = blockIdx.x * 256 + threadIdx.x;
  if (t >= 294912) return;
  const float* src; int Nn; int base;
  if      (t < 65536)  { src = wv; Nn = 256; base = 0; }
  else if (t < 131072) { src = wo; Nn = 256; base = 65536; }
  else if (t < 163840) { src = wa; Nn = 128; base = 131072; }
  else if (t < 229376) { src = wu; Nn = 256; base = 163840; }
  else                 { src = wf; Nn = 256; base = 229376; }
  const int local = t - base;
  const int n = local >> 8, k = local & 255;
  wt[t] = f2bf(src[k * Nn + n]);
}

// ---- 64x64-tile bf16 MFMA GEMM, BK=64, double-buffered LDS ----
// 1-D grid, XCD-chunk swizzled: each XCD owns a contiguous band-slab with all
// its column-blocks adjacent in time -> A-band re-reads are same-XCD L2 hits.
// A_MODE: 0 = bf16 A; 1 = f32 A (inline convert); 2 = f32 A + f32 A2 (sum, convert)
// C = A @ Bt^T + bias [+ RES];  Bt: [N][256] bf16 pre-transposed weights.
template<int NCOL, int A_MODE, bool OUT_BF16, bool ADD_RES>
__global__ __launch_bounds__(256) void gemm64(
    const void* __restrict__ Av, const float* __restrict__ A2,
    const unsigned short* __restrict__ Bt,
    const float* __restrict__ biasA, const float* __restrict__ biasB,
    const float* __restrict__ RES, void* __restrict__ Cv, int N)
{
  __shared__ unsigned short As[2][64*64];   // [row][k] bf16, XOR-swizzled 128B rows
  __shared__ unsigned short Bs[2][64*64];

  const int nwg = 416 * NCOL;               // divisible by 8
  const int lin = blockIdx.x;
  const int swz = (lin & 7) * (nwg >> 3) + (lin >> 3);
  const int brow = (swz / NCOL) * 64;
  const int bcol = (swz % NCOL) * 64;

  const int tid  = threadIdx.x;
  const int wid  = tid >> 6, lane = tid & 63;
  const int wr   = wid >> 1, wc = wid & 1;
  const int fr   = lane & 15, fg = lane >> 4;

  const int srow = tid >> 3;         // 0..31
  const int slot = (tid & 7) << 4;   // byte col 0..112
  const int ke0  = (tid & 7) << 3;   // element col 0..56

  f32x4 acc[2][2];
  #pragma unroll
  for (int m = 0; m < 2; ++m)
    #pragma unroll
    for (int n = 0; n < 2; ++n)
      acc[m][n] = (f32x4){0.f, 0.f, 0.f, 0.f};

  uint4 a_st[2], b_st[2];

  auto stage = [&](int k0) {
    #pragma unroll
    for (int c = 0; c < 2; ++c) {
      const int row = c * 32 + srow;
      const int ke  = k0 + ke0;
      b_st[c] = *(const uint4*)(Bt + (size_t)(bcol + row) * 256 + ke);
      if (A_MODE == 0) {
        a_st[c] = *(const uint4*)((const unsigned short*)Av + (size_t)(brow + row) * 256 + ke);
      } else {
        const int gr = brow + row;
        float4 f0 = make_float4(0.f,0.f,0.f,0.f), f1 = f0;
        if (gr < M_ROWS) {
          f0 = ld4((const float*)Av + (size_t)gr * 256 + ke);
          f1 = ld4((const float*)Av + (size_t)gr * 256 + ke + 4);
          if (A_MODE == 2) {
            float4 g0 = ld4(A2 + (size_t)gr * 256 + ke);
            float4 g1 = ld4(A2 + (size_t)gr * 256 + ke + 4);
            f0.x += g0.x; f0.y += g0.y; f0.z += g0.z; f0.w += g0.w;
            f1.x += g1.x; f1.y += g1.y; f1.z += g1.z; f1.w += g1.w;
          }
        }
        a_st[c].x = pk2(f0.x, f0.y); a_st[c].y = pk2(f0.z, f0.w);
        a_st[c].z = pk2(f1.x, f1.y); a_st[c].w = pk2(f1.z, f1.w);
      }
    }
  };

  auto write_lds = [&](int buf) {
    #pragma unroll
    for (int c = 0; c < 2; ++c) {
      const int row = c * 32 + srow;
      const int sw  = slot ^ ((row & 7) << 4);
      *(uint4*)((char*)&As[buf][0] + row * 128 + sw) = a_st[c];
      *(uint4*)((char*)&Bs[buf][0] + row * 128 + sw) = b_st[c];
    }
  };

  auto compute = [&](int buf) {
    #pragma unroll
    for (int kk = 0; kk < 2; ++kk) {
      const int kb = kk * 64 + fg * 16;
      bf16x8 af[2], bf[2];
      #pragma unroll
      for (int m = 0; m < 2; ++m) {
        const int r = wr * 32 + m * 16 + fr;
        af[m] = *(const bf16x8*)((const char*)&As[buf][0] + r * 128 + (kb ^ ((r & 7) << 4)));
      }
      #pragma unroll
      for (int n = 0; n < 2; ++n) {
        const int r = wc * 32 + n * 16 + fr;
        bf[n] = *(const bf16x8*)((const char*)&Bs[buf][0] + r * 128 + (kb ^ ((r & 7) << 4)));
      }
      #pragma unroll
      for (int m = 0; m < 2; ++m)
        #pragma unroll
        for (int n = 0; n < 2; ++n)
          acc[m][n] = __builtin_amdgcn_mfma_f32_16x16x32_bf16(af[m], bf[n], acc[m][n], 0, 0, 0);
    }
  };

  stage(0);
  write_lds(0);
  #pragma unroll
  for (int t = 0; t < 4; ++t) {
    if (t < 3) stage((t + 1) * 64);     // global loads in flight during compute
    __syncthreads();                    // buf[t&1] ready for all waves
    compute(t & 1);
    if (t < 3) write_lds((t + 1) & 1);  // other buffer; next barrier protects readers
  }

  // epilogue
  const int cn0 = bcol + wc * 32 + fr;
  const int cn1 = cn0 + 16;
  const float bn0 = (cn0 < 256) ? biasA[cn0] : biasB[cn0 - 256];
  const float bn1 = (cn1 < 256) ? biasA[cn1] : biasB[cn1 - 256];
  #pragma unroll
  for (int m = 0; m < 2; ++m) {
    #pragma unroll
    for (int j = 0; j < 4; ++j) {
      const int r = brow + wr * 32 + m * 16 + fg * 4 + j;
      if (r >= M_ROWS) continue;
      float v0 = acc[m][0][j] + bn0;
      float v1 = acc[m][1][j] + bn1;
      if (ADD_RES) {
        v0 += RES[(size_t)r * 256 + cn0];
        v1 += RES[(size_t)r * 256 + cn1];
      }
      if (OUT_BF16) {
        ((unsigned short*)Cv)[(size_t)r * N + cn0] = f2bf(v0);
        ((unsigned short*)Cv)[(size_t)r * N + cn1] = f2bf(v1);
      } else {
        ((float*)Cv)[(size_t)r * N + cn0] = v0;
        ((float*)Cv)[(size_t)r * N + cn1] = v1;
      }
    }
  }
}

// ---- deformable sampling: 8 queries/block, 4 lanes per (q,h), 8 ch/lane ----
// oa: fused (M,384) f32: [0:256) = offsets, [256:384) = attn logits
__global__ __launch_bounds__(256) void msda4(
    const unsigned short* __restrict__ v, const float* __restrict__ oa,
    const float* __restrict__ ref, unsigned short* __restrict__ attout)
{
  constexpr int LW[4] = {100, 50, 25, 13};
  constexpr int LS[4] = {0, 10000, 12500, 13125};

  __shared__ int4   sidx[8][8][16];   // [qi][h][p^pmask] corner BYTE offsets
  __shared__ float4 swt [8][8][16];   // premultiplied weights

  const int nwg = (M_ROWS + 7) / 8;   // 3324
  const int qq = nwg >> 3, rr = nwg & 7;
  const int xcd = blockIdx.x & 7, sub = blockIdx.x >> 3;
  const int wg = (xcd < rr ? xcd * (qq + 1) : rr * (qq + 1) + (xcd - rr) * qq) + sub;

  const int tid = threadIdx.x;
  const int qi  = tid >> 5;          // query in block 0..7
  const int h   = (tid >> 2) & 7;    // head
  const int lq  = tid & 3;           // level (phase1) / channel-octet (phase2)
  const int bq  = wg * 8 + qi;
  const bool active = bq < M_ROWS;
  const int b = (bq >= NQ) ? 1 : 0;
  const int pmask = (h << 1) | (qi & 1);   // distinct per quad within a wave -> bank spread

  if (active) {
    const int l = lq;
    const int W = LW[l];
    const float fD = (float)W;

    float4 lg4 = ld4(oa + (size_t)bq * 384 + 256 + h * 16 + l * 4);
    float mx = fmaxf(fmaxf(lg4.x, lg4.y), fmaxf(lg4.z, lg4.w));
    mx = fmaxf(mx, __shfl_xor(mx, 1));
    mx = fmaxf(mx, __shfl_xor(mx, 2));
    float e0 = __expf(lg4.x - mx), e1 = __expf(lg4.y - mx);
    float e2 = __expf(lg4.z - mx), e3 = __expf(lg4.w - mx);
    float s = e0 + e1 + e2 + e3;
    s += __shfl_xor(s, 1);
    s += __shfl_xor(s, 2);
    const float inv = 1.f / s;
    const float ee[4] = {e0 * inv, e1 * inv, e2 * inv, e3 * inv};

    const float rx = ref[(size_t)bq * 8 + l * 2];
    const float ry = ref[(size_t)bq * 8 + l * 2 + 1];
    float4 o1 = ld4(oa + (size_t)bq * 384 + h * 32 + l * 8);
    float4 o2 = ld4(oa + (size_t)bq * 384 + h * 32 + l * 8 + 4);
    const float oxy[8] = {o1.x, o1.y, o1.z, o1.w, o2.x, o2.y, o2.z, o2.w};
    const int baseb = (LS[l] * 256 + h * 32) * 2;   // byte offset into v

    #pragma unroll
    for (int j = 0; j < 4; ++j) {
      const float x = (rx + oxy[2*j]   / fD) * fD - 0.5f;
      const float y = (ry + oxy[2*j+1] / fD) * fD - 0.5f;
      const float x0f = floorf(x), y0f = floorf(y);
      const float lx = x - x0f, ly = y - y0f;
      const int x0 = (int)x0f, y0 = (int)y0f;
      const int x1 = x0 + 1,  y1 = y0 + 1;
      const int cx0 = min(max(x0, 0), W - 1), cx1 = min(max(x1, 0), W - 1);
      const int cy0 = min(max(y0, 0), W - 1), cy1 = min(max(y1, 0), W - 1);
      const float f00 = (x0 >= 0 && x0 < W && y0 >= 0 && y0 < W) ? 1.f : 0.f;
      const float f10 = (x1 >= 0 && x1 < W && y0 >= 0 && y0 < W) ? 1.f : 0.f;
      const float f01 = (x0 >= 0 && x0 < W && y1 >= 0 && y1 < W) ? 1.f : 0.f;
      const float f11 = (x1 >= 0 && x1 < W && y1 >= 0 && y1 < W) ? 1.f : 0.f;
      const float wt = ee[j];
      const int pi = (l * 4 + j) ^ pmask;
      sidx[qi][h][pi] = make_int4(baseb + (cy0 * W + cx0) * 512,
                                  baseb + (cy0 * W + cx1) * 512,
                                  baseb + (cy1 * W + cx0) * 512,
                                  baseb + (cy1 * W + cx1) * 512);
      swt[qi][h][pi] = make_float4(wt * (1.f - lx) * (1.f - ly) * f00,
                                   wt * lx * (1.f - ly) * f10,
                                   wt * (1.f - lx) * ly * f01,
                                   wt * lx * ly * f11);
    }
  }
  __syncthreads();

  if (active) {
    const char* vb = (const char*)v + (size_t)b * NV * 512 + lq * 16;
    float acc[8] = {0.f, 0.f, 0.f, 0.f, 0.f, 0.f, 0.f, 0.f};
    #pragma unroll
    for (int p = 0; p < 16; ++p) {
      const int4   ix = sidx[qi][h][p ^ pmask];
      const float4 w4 = swt[qi][h][p ^ pmask];
      uint4 c0 = *(const uint4*)(vb + ix.x);
      uint4 c1 = *(const uint4*)(vb + ix.y);
      uint4 c2 = *(const uint4*)(vb + ix.z);
      uint4 c3 = *(const uint4*)(vb + ix.w);
      acc[0] = fmaf(w4.x, bfu_lo(c0.x), acc[0]); acc[1] = fmaf(w4.x, bfu_hi(c0.x), acc[1]);
      acc[2] = fmaf(w4.x, bfu_lo(c0.y), acc[2]); acc[3] = fmaf(w4.x, bfu_hi(c0.y), acc[3]);
      acc[4] = fmaf(w4.x, bfu_lo(c0.z), acc[4]); acc[5] = fmaf(w4.x, bfu_hi(c0.z), acc[5]);
      acc[6] = fmaf(w4.x, bfu_lo(c0.w), acc[6]); acc[7] = fmaf(w4.x, bfu_hi(c0.w), acc[7]);
      acc[0] = fmaf(w4.y, bfu_lo(c1.x), acc[0]); acc[1] = fmaf(w4.y, bfu_hi(c1.x), acc[1]);
      acc[2] = fmaf(w4.y, bfu_lo(c1.y), acc[2]); acc[3] = fmaf(w4.y, bfu_hi(c1.y), acc[3]);
      acc[4] = fmaf(w4.y, bfu_lo(c1.z), acc[4]); acc[5] = fmaf(w4.y, bfu_hi(c1.z), acc[5]);
      acc[6] = fmaf(w4.y, bfu_lo(c1.w), acc[6]); acc[7] = fmaf(w4.y, bfu_hi(c1.w), acc[7]);
      acc[0] = fmaf(w4.z, bfu_lo(c2.x), acc[0]); acc[1] = fmaf(w4.z, bfu_hi(c2.x), acc[1]);
      acc[2] = fmaf(w4.z, bfu_lo(c2.y), acc[2]); acc[3] = fmaf(w4.z, bfu_hi(c2.y), acc[3]);
      acc[4] = fmaf(w4.z, bfu_lo(c2.z), acc[4]); acc[5] = fmaf(w4.z, bfu_hi(c2.z), acc[5]);
      acc[6] = fmaf(w4.z, bfu_lo(c2.w), acc[6]); acc[7] = fmaf(w4.z, bfu_hi(c2.w), acc[7]);
      acc[0] = fmaf(w4.w, bfu_lo(c3.x), acc[0]); acc[1] = fmaf(w4.w, bfu_hi(c3.x), acc[1]);
      acc[2] = fmaf(w4.w, bfu_lo(c3.y), acc[2]); acc[3] = fmaf(w4.w, bfu_hi(c3.y), acc[3]);
      acc[4] = fmaf(w4.w, bfu_lo(c3.z), acc[4]); acc[5] = fmaf(w4.w, bfu_hi(c3.z), acc[5]);
      acc[6] = fmaf(w4.w, bfu_lo(c3.w), acc[6]); acc[7] = fmaf(w4.w, bfu_hi(c3.w), acc[7]);
    }
    uint4 pk;
    pk.x = pk2(acc[0], acc[1]);
    pk.y = pk2(acc[2], acc[3]);
    pk.z = pk2(acc[4], acc[5]);
    pk.w = pk2(acc[6], acc[7]);
    *(uint4*)(attout + (size_t)bq * 256 + h * 32 + lq * 8) = pk;
  }
}

extern "C" void kernel_launch(void* const* d_in, const int* in_sizes, int n_in,
                              void* d_out, int out_size, void* d_ws, size_t ws_size,
                              hipStream_t stream) {
  const float* query  = (const float*)d_in[0];
  const float* value  = (const float*)d_in[2];
  const float* qpos   = (const float*)d_in[3];
  const float* refpts = (const float*)d_in[4];
  const float* W_value = (const float*)d_in[8];
  const float* b_value = (const float*)d_in[9];
  const float* W_off   = (const float*)d_in[10];
  const float* b_off   = (const float*)d_in[11];
  const float* W_attn  = (const float*)d_in[12];
  const float* b_attn  = (const float*)d_in[13];
  const float* W_out   = (const float*)d_in[14];
  const float* b_out   = (const float*)d_in[15];
  const float* W_ffn   = (const float*)d_in[16];
  const float* b_ffn   = (const float*)d_in[17];
  float* out = (float*)d_out;

  // workspace layout (~82.4 MB)
  float* oa_buf = (float*)d_ws;                                   // (MP,384) f32
  unsigned short* vbuf = (unsigned short*)(oa_buf + (size_t)MP * 384); // (MP,256) bf16
  unsigned short* R1   = vbuf + (size_t)MP * 256;                 // attout bf16
  unsigned short* R2   = R1 + (size_t)MP * 256;                   // tmp bf16
  unsigned short* wts  = R2 + (size_t)MP * 256;                   // transposed weights
  unsigned short* wv_t = wts;
  unsigned short* woa_t = wts + 65536;    // [W_off^T ; W_attn^T] rows 0..383
  unsigned short* wu_t = wts + 163840;
  unsigned short* wf_t = wts + 229376;

  const dim3 blk(256);

  prep_w<<<dim3(1152), blk, 0, stream>>>(W_value, W_off, W_attn, W_out, W_ffn, wts);

  // v = value @ W_value + b  -> bf16 (inline f32->bf16 A conversion)
  gemm64<4,1,true,false><<<dim3(1664), blk, 0, stream>>>(
      value, nullptr, wv_t, b_value, b_value, nullptr, vbuf, 256);
  // [off | attn] = (query+qpos) @ [W_off;W_attn] + [b_off;b_attn] -> f32 (M,384)
  gemm64<6,2,false,false><<<dim3(2496), blk, 0, stream>>>(
      query, qpos, woa_t, b_off, b_attn, nullptr, oa_buf, 384);
  // deformable sampling -> attout bf16
  msda4<<<dim3((M_ROWS + 7) / 8), blk, 0, stream>>>(vbuf, oa_buf, refpts, R1);
  // tmp = attout @ W_out + b_out + query (residual) -> bf16
  gemm64<4,0,true,true><<<dim3(1664), blk, 0, stream>>>(
      R1, nullptr, wu_t, b_out, b_out, query, R2, 256);
  // out = tmp @ W_ffn + b_ffn -> f32
  gemm64<4,0,false,false><<<dim3(1664), blk, 0, stream>>>(
      R2, nullptr, wf_t, b_ffn, b_ffn, nullptr, (void*)out, 256);
}

// Round 8
// 138.307 us; speedup vs baseline: 1.6304x; 1.3434x over previous
//
#include <hip/hip_runtime.h>
#include <hip/hip_bf16.h>
#include <math.h>

#define NQ 13294
#define NV 13294
#define M_ROWS (2*NQ)     // 26588
#define MP 26624          // padded row count (416*64)

typedef __attribute__((ext_vector_type(8))) short bf16x8;
typedef __attribute__((ext_vector_type(4))) float f32x4;

__device__ __forceinline__ float4 ld4(const float* p){ return *(const float4*)p; }
__device__ __forceinline__ float bfu_lo(unsigned int u){ return __uint_as_float(u << 16); }
__device__ __forceinline__ float bfu_hi(unsigned int u){ return __uint_as_float(u & 0xffff0000u); }
__device__ __forceinline__ unsigned short f2bf(float f){
  unsigned int u = __float_as_uint(f);
  u += 0x7fffu + ((u >> 16) & 1u);   // RNE
  return (unsigned short)(u >> 16);
}
__device__ __forceinline__ unsigned int pk2(float a, float b){
  return (unsigned int)f2bf(a) | ((unsigned int)f2bf(b) << 16);
}
__device__ __forceinline__ void gl_lds16(const unsigned short* g, unsigned short* l) {
  __builtin_amdgcn_global_load_lds(
      (const __attribute__((address_space(1))) unsigned int*)g,
      (__attribute__((address_space(3))) unsigned int*)l, 16, 0, 0);
}

// ---- prep: value -> bf16, (query+qpos) -> bf16, zero-pad rows M..MP ----
__global__ __launch_bounds__(256) void prep_a(
    const float* __restrict__ value, const float* __restrict__ query,
    const float* __restrict__ qpos,
    unsigned short* __restrict__ val_bf, unsigned short* __restrict__ q_bf)
{
  const int total = MP * 64;   // float4 groups
  for (int i = blockIdx.x * 256 + threadIdx.x; i < total; i += gridDim.x * 256) {
    const int e = i * 4;
    ushort4 a = make_ushort4(0,0,0,0), b = make_ushort4(0,0,0,0);
    if (e < M_ROWS * 256) {
      float4 v4 = ld4(value + e);
      a = make_ushort4(f2bf(v4.x), f2bf(v4.y), f2bf(v4.z), f2bf(v4.w));
      float4 q4 = ld4(query + e);
      float4 p4 = ld4(qpos + e);
      b = make_ushort4(f2bf(q4.x+p4.x), f2bf(q4.y+p4.y), f2bf(q4.z+p4.z), f2bf(q4.w+p4.w));
    }
    *(ushort4*)(val_bf + e) = a;
    *(ushort4*)(q_bf   + e) = b;
  }
}

// ---- prep: transpose 5 weights f32 [K][N] -> bf16 [N][K] (K=256) ----
__global__ __launch_bounds__(256) void prep_w(
    const float* __restrict__ wv, const float* __restrict__ wo,
    const float* __restrict__ wa, const float* __restrict__ wu,
    const float* __restrict__ wf, unsigned short* __restrict__ wt)
{
  int t = blockIdx.x * 256 + threadIdx.x;
  if (t >= 294912) return;
  const float* src; int Nn; int base;
  if      (t < 65536)  { src = wv; Nn = 256; base = 0; }
  else if (t < 131072) { src = wo; Nn = 256; base = 65536; }
  else if (t < 163840) { src = wa; Nn = 128; base = 131072; }
  else if (t < 229376) { src = wu; Nn = 256; base = 163840; }
  else                 { src = wf; Nn = 256; base = 229376; }
  const int local = t - base;
  const int n = local >> 8, k = local & 255;
  wt[t] = f2bf(src[k * Nn + n]);
}

// ---- 64x64-tile bf16 MFMA GEMM, full-K (4 tiles) LDS via global_load_lds ----
// All staging loads issued up front (no VGPR round-trip); one barrier; 32 MFMA;
// coalesced epilogue through LDS. XCD-chunk swizzled 1-D grid.
// C = A @ Bt^T + bias [+ RES]; A:[MP][256] bf16, Bt:[N][256] bf16.
template<int NCOL, bool OUT_BF16, bool ADD_RES>
__global__ __launch_bounds__(256) void gemm_gl(
    const unsigned short* __restrict__ A, const unsigned short* __restrict__ Bt,
    const float* __restrict__ biasA, const float* __restrict__ biasB,
    const float* __restrict__ RES, void* __restrict__ Cv, int N)
{
  __shared__ unsigned short lds[32768];   // As [0,16384) | Bs [16384,32768)  (64 KB)

  const int nwg = 416 * NCOL;             // divisible by 8
  const int lin = blockIdx.x;
  const int swz = (lin & 7) * (nwg >> 3) + (lin >> 3);
  const int brow = (swz / NCOL) * 64;
  const int bcol = (swz % NCOL) * 64;

  const int tid  = threadIdx.x;
  const int wid  = tid >> 6, lane = tid & 63;
  const int wr   = wid >> 1, wc = wid & 1;
  const int fr   = lane & 15, fg = lane >> 4;

  // ---- stage all of K: per wave, per tile, 2 chunks of 8 rows x 128 B ----
  // LDS linear [row][slot]; global slot pre-XOR'd so ds_read can swizzle.
  {
    const int r0   = lane >> 3;      // 0..7
    const int slot = lane & 7;       // 16B slot
    #pragma unroll
    for (int t = 0; t < 4; ++t) {
      #pragma unroll
      for (int c = 0; c < 2; ++c) {
        const int row = (wid * 2 + c) * 8 + r0;     // 0..63
        const int gsl = slot ^ (row & 7);
        gl_lds16(A  + (size_t)(brow + row) * 256 + t * 64 + (gsl << 3),
                 &lds[t * 4096 + (wid * 2 + c) * 512]);
        gl_lds16(Bt + (size_t)(bcol + row) * 256 + t * 64 + (gsl << 3),
                 &lds[16384 + t * 4096 + (wid * 2 + c) * 512]);
      }
    }
  }
  __syncthreads();   // vmcnt(0) drain + barrier: all tiles resident

  f32x4 acc[2][2];
  #pragma unroll
  for (int m = 0; m < 2; ++m)
    #pragma unroll
    for (int n = 0; n < 2; ++n)
      acc[m][n] = (f32x4){0.f, 0.f, 0.f, 0.f};

  #pragma unroll
  for (int t = 0; t < 4; ++t) {
    const char* as = (const char*)&lds[t * 4096];
    const char* bs = (const char*)&lds[16384 + t * 4096];
    #pragma unroll
    for (int kk = 0; kk < 2; ++kk) {
      const int kb = kk * 64 + fg * 16;
      bf16x8 af[2], bfv[2];
      #pragma unroll
      for (int m = 0; m < 2; ++m) {
        const int r = wr * 32 + m * 16 + fr;
        af[m] = *(const bf16x8*)(as + r * 128 + (kb ^ ((r & 7) << 4)));
      }
      #pragma unroll
      for (int n = 0; n < 2; ++n) {
        const int r = wc * 32 + n * 16 + fr;
        bfv[n] = *(const bf16x8*)(bs + r * 128 + (kb ^ ((r & 7) << 4)));
      }
      #pragma unroll
      for (int m = 0; m < 2; ++m)
        #pragma unroll
        for (int n = 0; n < 2; ++n)
          acc[m][n] = __builtin_amdgcn_mfma_f32_16x16x32_bf16(af[m], bfv[n], acc[m][n], 0, 0, 0);
    }
  }

  // ---- epilogue: acc -> LDS (f32 64x64) -> coalesced row stores ----
  __syncthreads();
  float* csh = (float*)lds;    // 16 KB, reuses As space
  const int c0 = bcol + wc * 32 + fr;
  const int c1 = c0 + 16;
  const float bn0 = (c0 < 256) ? biasA[c0] : biasB[c0 - 256];
  const float bn1 = (c1 < 256) ? biasA[c1] : biasB[c1 - 256];
  #pragma unroll
  for (int m = 0; m < 2; ++m)
    #pragma unroll
    for (int j = 0; j < 4; ++j) {
      const int row = wr * 32 + m * 16 + fg * 4 + j;
      csh[row * 64 + wc * 32 + fr]      = acc[m][0][j] + bn0;
      csh[row * 64 + wc * 32 + 16 + fr] = acc[m][1][j] + bn1;
    }
  __syncthreads();
  #pragma unroll
  for (int i = 0; i < 4; ++i) {
    const int rl = i * 16 + (tid >> 4);
    const int gr = brow + rl;
    if (gr >= M_ROWS) continue;
    const int c4 = (tid & 15) * 4;
    float4 v = *(const float4*)&csh[rl * 64 + c4];
    if (ADD_RES) {
      float4 q = ld4(RES + (size_t)gr * 256 + bcol + c4);
      v.x += q.x; v.y += q.y; v.z += q.z; v.w += q.w;
    }
    if (OUT_BF16) {
      ushort4 pk = make_ushort4(f2bf(v.x), f2bf(v.y), f2bf(v.z), f2bf(v.w));
      *(ushort4*)&((unsigned short*)Cv)[(size_t)gr * N + bcol + c4] = pk;
    } else {
      *(float4*)&((float*)Cv)[(size_t)gr * N + bcol + c4] = v;
    }
  }
}

// ---- deformable sampling: 8 queries/block, 4 lanes per (q,h), 8 ch/lane ----
// oa: fused (M,384) f32: [0:256) = offsets, [256:384) = attn logits
__global__ __launch_bounds__(256) void msda4(
    const unsigned short* __restrict__ v, const float* __restrict__ oa,
    const float* __restrict__ ref, unsigned short* __restrict__ attout)
{
  constexpr int LW[4] = {100, 50, 25, 13};
  constexpr int LS[4] = {0, 10000, 12500, 13125};

  __shared__ int4   sidx[8][8][16];   // [qi][h][p^pmask] corner BYTE offsets
  __shared__ float4 swt [8][8][16];   // premultiplied weights

  const int nwg = (M_ROWS + 7) / 8;   // 3324
  const int qq = nwg >> 3, rr = nwg & 7;
  const int xcd = blockIdx.x & 7, sub = blockIdx.x >> 3;
  const int wg = (xcd < rr ? xcd * (qq + 1) : rr * (qq + 1) + (xcd - rr) * qq) + sub;

  const int tid = threadIdx.x;
  const int qi  = tid >> 5;          // query in block 0..7
  const int h   = (tid >> 2) & 7;    // head
  const int lq  = tid & 3;           // level (phase1) / channel-octet (phase2)
  const int bq  = wg * 8 + qi;
  const bool active = bq < M_ROWS;
  const int b = (bq >= NQ) ? 1 : 0;
  const int pmask = (h << 1) | (qi & 1);   // distinct per quad within a wave -> bank spread

  if (active) {
    const int l = lq;
    const int W = LW[l];
    const float fD = (float)W;

    float4 lg4 = ld4(oa + (size_t)bq * 384 + 256 + h * 16 + l * 4);
    float mx = fmaxf(fmaxf(lg4.x, lg4.y), fmaxf(lg4.z, lg4.w));
    mx = fmaxf(mx, __shfl_xor(mx, 1));
    mx = fmaxf(mx, __shfl_xor(mx, 2));
    float e0 = __expf(lg4.x - mx), e1 = __expf(lg4.y - mx);
    float e2 = __expf(lg4.z - mx), e3 = __expf(lg4.w - mx);
    float s = e0 + e1 + e2 + e3;
    s += __shfl_xor(s, 1);
    s += __shfl_xor(s, 2);
    const float inv = 1.f / s;
    const float ee[4] = {e0 * inv, e1 * inv, e2 * inv, e3 * inv};

    const float rx = ref[(size_t)bq * 8 + l * 2];
    const float ry = ref[(size_t)bq * 8 + l * 2 + 1];
    float4 o1 = ld4(oa + (size_t)bq * 384 + h * 32 + l * 8);
    float4 o2 = ld4(oa + (size_t)bq * 384 + h * 32 + l * 8 + 4);
    const float oxy[8] = {o1.x, o1.y, o1.z, o1.w, o2.x, o2.y, o2.z, o2.w};
    const int baseb = (LS[l] * 256 + h * 32) * 2;   // byte offset into v

    #pragma unroll
    for (int j = 0; j < 4; ++j) {
      const float x = (rx + oxy[2*j]   / fD) * fD - 0.5f;
      const float y = (ry + oxy[2*j+1] / fD) * fD - 0.5f;
      const float x0f = floorf(x), y0f = floorf(y);
      const float lx = x - x0f, ly = y - y0f;
      const int x0 = (int)x0f, y0 = (int)y0f;
      const int x1 = x0 + 1,  y1 = y0 + 1;
      const int cx0 = min(max(x0, 0), W - 1), cx1 = min(max(x1, 0), W - 1);
      const int cy0 = min(max(y0, 0), W - 1), cy1 = min(max(y1, 0), W - 1);
      const float f00 = (x0 >= 0 && x0 < W && y0 >= 0 && y0 < W) ? 1.f : 0.f;
      const float f10 = (x1 >= 0 && x1 < W && y0 >= 0 && y0 < W) ? 1.f : 0.f;
      const float f01 = (x0 >= 0 && x0 < W && y1 >= 0 && y1 < W) ? 1.f : 0.f;
      const float f11 = (x1 >= 0 && x1 < W && y1 >= 0 && y1 < W) ? 1.f : 0.f;
      const float wt = ee[j];
      const int pi = (l * 4 + j) ^ pmask;
      sidx[qi][h][pi] = make_int4(baseb + (cy0 * W + cx0) * 512,
                                  baseb + (cy0 * W + cx1) * 512,
                                  baseb + (cy1 * W + cx0) * 512,
                                  baseb + (cy1 * W + cx1) * 512);
      swt[qi][h][pi] = make_float4(wt * (1.f - lx) * (1.f - ly) * f00,
                                   wt * lx * (1.f - ly) * f10,
                                   wt * (1.f - lx) * ly * f01,
                                   wt * lx * ly * f11);
    }
  }
  __syncthreads();

  if (active) {
    const char* vb = (const char*)v + (size_t)b * NV * 512 + lq * 16;
    float acc[8] = {0.f, 0.f, 0.f, 0.f, 0.f, 0.f, 0.f, 0.f};
    #pragma unroll
    for (int p = 0; p < 16; ++p) {
      const int4   ix = sidx[qi][h][p ^ pmask];
      const float4 w4 = swt[qi][h][p ^ pmask];
      uint4 c0 = *(const uint4*)(vb + ix.x);
      uint4 c1 = *(const uint4*)(vb + ix.y);
      uint4 c2 = *(const uint4*)(vb + ix.z);
      uint4 c3 = *(const uint4*)(vb + ix.w);
      acc[0] = fmaf(w4.x, bfu_lo(c0.x), acc[0]); acc[1] = fmaf(w4.x, bfu_hi(c0.x), acc[1]);
      acc[2] = fmaf(w4.x, bfu_lo(c0.y), acc[2]); acc[3] = fmaf(w4.x, bfu_hi(c0.y), acc[3]);
      acc[4] = fmaf(w4.x, bfu_lo(c0.z), acc[4]); acc[5] = fmaf(w4.x, bfu_hi(c0.z), acc[5]);
      acc[6] = fmaf(w4.x, bfu_lo(c0.w), acc[6]); acc[7] = fmaf(w4.x, bfu_hi(c0.w), acc[7]);
      acc[0] = fmaf(w4.y, bfu_lo(c1.x), acc[0]); acc[1] = fmaf(w4.y, bfu_hi(c1.x), acc[1]);
      acc[2] = fmaf(w4.y, bfu_lo(c1.y), acc[2]); acc[3] = fmaf(w4.y, bfu_hi(c1.y), acc[3]);
      acc[4] = fmaf(w4.y, bfu_lo(c1.z), acc[4]); acc[5] = fmaf(w4.y, bfu_hi(c1.z), acc[5]);
      acc[6] = fmaf(w4.y, bfu_lo(c1.w), acc[6]); acc[7] = fmaf(w4.y, bfu_hi(c1.w), acc[7]);
      acc[0] = fmaf(w4.z, bfu_lo(c2.x), acc[0]); acc[1] = fmaf(w4.z, bfu_hi(c2.x), acc[1]);
      acc[2] = fmaf(w4.z, bfu_lo(c2.y), acc[2]); acc[3] = fmaf(w4.z, bfu_hi(c2.y), acc[3]);
      acc[4] = fmaf(w4.z, bfu_lo(c2.z), acc[4]); acc[5] = fmaf(w4.z, bfu_hi(c2.z), acc[5]);
      acc[6] = fmaf(w4.z, bfu_lo(c2.w), acc[6]); acc[7] = fmaf(w4.z, bfu_hi(c2.w), acc[7]);
      acc[0] = fmaf(w4.w, bfu_lo(c3.x), acc[0]); acc[1] = fmaf(w4.w, bfu_hi(c3.x), acc[1]);
      acc[2] = fmaf(w4.w, bfu_lo(c3.y), acc[2]); acc[3] = fmaf(w4.w, bfu_hi(c3.y), acc[3]);
      acc[4] = fmaf(w4.w, bfu_lo(c3.z), acc[4]); acc[5] = fmaf(w4.w, bfu_hi(c3.z), acc[5]);
      acc[6] = fmaf(w4.w, bfu_lo(c3.w), acc[6]); acc[7] = fmaf(w4.w, bfu_hi(c3.w), acc[7]);
    }
    uint4 pk;
    pk.x = pk2(acc[0], acc[1]);
    pk.y = pk2(acc[2], acc[3]);
    pk.z = pk2(acc[4], acc[5]);
    pk.w = pk2(acc[6], acc[7]);
    *(uint4*)(attout + (size_t)bq * 256 + h * 32 + lq * 8) = pk;
  }
}

extern "C" void kernel_launch(void* const* d_in, const int* in_sizes, int n_in,
                              void* d_out, int out_size, void* d_ws, size_t ws_size,
                              hipStream_t stream) {
  const float* query  = (const float*)d_in[0];
  const float* value  = (const float*)d_in[2];
  const float* qpos   = (const float*)d_in[3];
  const float* refpts = (const float*)d_in[4];
  const float* W_value = (const float*)d_in[8];
  const float* b_value = (const float*)d_in[9];
  const float* W_off   = (const float*)d_in[10];
  const float* b_off   = (const float*)d_in[11];
  const float* W_attn  = (const float*)d_in[12];
  const float* b_attn  = (const float*)d_in[13];
  const float* W_out   = (const float*)d_in[14];
  const float* b_out   = (const float*)d_in[15];
  const float* W_ffn   = (const float*)d_in[16];
  const float* b_ffn   = (const float*)d_in[17];
  float* out = (float*)d_out;

  // workspace layout (~96 MB)
  float* oa_buf = (float*)d_ws;                                        // (MP,384) f32
  unsigned short* vbuf = (unsigned short*)(oa_buf + (size_t)MP * 384); // (MP,256) bf16
  unsigned short* AB1  = vbuf + (size_t)MP * 256;   // val_bf -> attout bf16
  unsigned short* AB2  = AB1 + (size_t)MP * 256;    // q_bf   -> tmp bf16
  unsigned short* wts  = AB2 + (size_t)MP * 256;    // transposed weights
  unsigned short* wv_t  = wts;
  unsigned short* woa_t = wts + 65536;   // [W_off^T ; W_attn^T] rows 0..383
  unsigned short* wu_t  = wts + 163840;
  unsigned short* wf_t  = wts + 229376;

  const dim3 blk(256);

  prep_w<<<dim3(1152), blk, 0, stream>>>(W_value, W_off, W_attn, W_out, W_ffn, wts);
  prep_a<<<dim3(2048), blk, 0, stream>>>(value, query, qpos, AB1, AB2);

  // v = value @ W_value + b  -> bf16
  gemm_gl<4,true,false><<<dim3(1664), blk, 0, stream>>>(
      AB1, wv_t, b_value, b_value, nullptr, vbuf, 256);
  // [off | attn] = (query+qpos) @ [W_off;W_attn] + [b_off;b_attn] -> f32 (M,384)
  gemm_gl<6,false,false><<<dim3(2496), blk, 0, stream>>>(
      AB2, woa_t, b_off, b_attn, nullptr, oa_buf, 384);
  // deformable sampling -> attout bf16 (overwrites AB1)
  msda4<<<dim3((M_ROWS + 7) / 8), blk, 0, stream>>>(vbuf, oa_buf, refpts, AB1);
  // tmp = attout @ W_out + b_out + query (residual) -> bf16 (overwrites AB2)
  gemm_gl<4,true,true><<<dim3(1664), blk, 0, stream>>>(
      AB1, wu_t, b_out, b_out, query, AB2, 256);
  // out = tmp @ W_ffn + b_ffn -> f32
  gemm_gl<4,false,false><<<dim3(1664), blk, 0, stream>>>(
      AB2, wf_t, b_ffn, b_ffn, nullptr, (void*)out, 256);
}

// Round 9
// 122.171 us; speedup vs baseline: 1.8458x; 1.1321x over previous
//
#include <hip/hip_runtime.h>
#include <hip/hip_bf16.h>
#include <math.h>

#define NQ 13294
#define NV 13294
#define M_ROWS (2*NQ)     // 26588
#define MP 26624          // padded row count (416*64)

typedef __attribute__((ext_vector_type(8))) short bf16x8;
typedef __attribute__((ext_vector_type(4))) float f32x4;

__device__ __forceinline__ float4 ld4(const float* p){ return *(const float4*)p; }
__device__ __forceinline__ float bfu_lo(unsigned int u){ return __uint_as_float(u << 16); }
__device__ __forceinline__ float bfu_hi(unsigned int u){ return __uint_as_float(u & 0xffff0000u); }
__device__ __forceinline__ unsigned short f2bf(float f){
  unsigned int u = __float_as_uint(f);
  u += 0x7fffu + ((u >> 16) & 1u);   // RNE
  return (unsigned short)(u >> 16);
}
__device__ __forceinline__ unsigned int pk2(float a, float b){
  return (unsigned int)f2bf(a) | ((unsigned int)f2bf(b) << 16);
}
__device__ __forceinline__ void gl_lds16(const unsigned short* g, unsigned short* l) {
  __builtin_amdgcn_global_load_lds(
      (const __attribute__((address_space(1))) unsigned int*)g,
      (__attribute__((address_space(3))) unsigned int*)l, 16, 0, 0);
}

// ---- prep: value->bf16, (query+qpos)->bf16 (zero-padded), + 5 weight transposes ----
__global__ __launch_bounds__(256) void prep_all(
    const float* __restrict__ value, const float* __restrict__ query,
    const float* __restrict__ qpos,
    unsigned short* __restrict__ val_bf, unsigned short* __restrict__ q_bf,
    const float* __restrict__ wv, const float* __restrict__ wo,
    const float* __restrict__ wa, const float* __restrict__ wu,
    const float* __restrict__ wf, unsigned short* __restrict__ wt)
{
  const int total = MP * 64;   // float4 groups
  for (int i = blockIdx.x * 256 + threadIdx.x; i < total; i += gridDim.x * 256) {
    const int e = i * 4;
    ushort4 a = make_ushort4(0,0,0,0), b = make_ushort4(0,0,0,0);
    if (e < M_ROWS * 256) {
      float4 v4 = ld4(value + e);
      a = make_ushort4(f2bf(v4.x), f2bf(v4.y), f2bf(v4.z), f2bf(v4.w));
      float4 q4 = ld4(query + e);
      float4 p4 = ld4(qpos + e);
      b = make_ushort4(f2bf(q4.x+p4.x), f2bf(q4.y+p4.y), f2bf(q4.z+p4.z), f2bf(q4.w+p4.w));
    }
    *(ushort4*)(val_bf + e) = a;
    *(ushort4*)(q_bf   + e) = b;
  }
  for (int t = blockIdx.x * 256 + threadIdx.x; t < 294912; t += gridDim.x * 256) {
    const float* src; int Nn; int base;
    if      (t < 65536)  { src = wv; Nn = 256; base = 0; }
    else if (t < 131072) { src = wo; Nn = 256; base = 65536; }
    else if (t < 163840) { src = wa; Nn = 128; base = 131072; }
    else if (t < 229376) { src = wu; Nn = 256; base = 163840; }
    else                 { src = wf; Nn = 256; base = 229376; }
    const int local = t - base;
    const int n = local >> 8, k = local & 255;
    wt[t] = f2bf(src[k * Nn + n]);
  }
}

// ---- 64x64-tile bf16 MFMA GEMM, full-K LDS via global_load_lds ----
// OUT_MODE: 0 = f32 rows, 1 = bf16 rows, 2 = bf16 head-split vbuf2[head][row][32]
template<int NCOL, int OUT_MODE, bool ADD_RES>
__global__ __launch_bounds__(256) void gemm_gl(
    const unsigned short* __restrict__ A, const unsigned short* __restrict__ Bt,
    const float* __restrict__ biasA, const float* __restrict__ biasB,
    const float* __restrict__ RES, void* __restrict__ Cv, int N)
{
  __shared__ unsigned short lds[32768];   // As [0,16384) | Bs [16384,32768)

  const int nwg = 416 * NCOL;             // divisible by 8
  const int lin = blockIdx.x;
  const int swz = (lin & 7) * (nwg >> 3) + (lin >> 3);
  const int brow = (swz / NCOL) * 64;
  const int bcol = (swz % NCOL) * 64;

  const int tid  = threadIdx.x;
  const int wid  = tid >> 6, lane = tid & 63;
  const int wr   = wid >> 1, wc = wid & 1;
  const int fr   = lane & 15, fg = lane >> 4;

  {
    const int r0   = lane >> 3;      // 0..7
    const int slot = lane & 7;       // 16B slot
    #pragma unroll
    for (int t = 0; t < 4; ++t) {
      #pragma unroll
      for (int c = 0; c < 2; ++c) {
        const int row = (wid * 2 + c) * 8 + r0;     // 0..63
        const int gsl = slot ^ (row & 7);
        gl_lds16(A  + (size_t)(brow + row) * 256 + t * 64 + (gsl << 3),
                 &lds[t * 4096 + (wid * 2 + c) * 512]);
        gl_lds16(Bt + (size_t)(bcol + row) * 256 + t * 64 + (gsl << 3),
                 &lds[16384 + t * 4096 + (wid * 2 + c) * 512]);
      }
    }
  }
  __syncthreads();

  f32x4 acc[2][2];
  #pragma unroll
  for (int m = 0; m < 2; ++m)
    #pragma unroll
    for (int n = 0; n < 2; ++n)
      acc[m][n] = (f32x4){0.f, 0.f, 0.f, 0.f};

  #pragma unroll
  for (int t = 0; t < 4; ++t) {
    const char* as = (const char*)&lds[t * 4096];
    const char* bs = (const char*)&lds[16384 + t * 4096];
    #pragma unroll
    for (int kk = 0; kk < 2; ++kk) {
      const int kb = kk * 64 + fg * 16;
      bf16x8 af[2], bfv[2];
      #pragma unroll
      for (int m = 0; m < 2; ++m) {
        const int r = wr * 32 + m * 16 + fr;
        af[m] = *(const bf16x8*)(as + r * 128 + (kb ^ ((r & 7) << 4)));
      }
      #pragma unroll
      for (int n = 0; n < 2; ++n) {
        const int r = wc * 32 + n * 16 + fr;
        bfv[n] = *(const bf16x8*)(bs + r * 128 + (kb ^ ((r & 7) << 4)));
      }
      #pragma unroll
      for (int m = 0; m < 2; ++m)
        #pragma unroll
        for (int n = 0; n < 2; ++n)
          acc[m][n] = __builtin_amdgcn_mfma_f32_16x16x32_bf16(af[m], bfv[n], acc[m][n], 0, 0, 0);
    }
  }

  // ---- epilogue: acc -> LDS (f32 64x64) -> coalesced stores ----
  __syncthreads();
  float* csh = (float*)lds;
  const int c0 = bcol + wc * 32 + fr;
  const int c1 = c0 + 16;
  const float bn0 = (c0 < 256) ? biasA[c0] : biasB[c0 - 256];
  const float bn1 = (c1 < 256) ? biasA[c1] : biasB[c1 - 256];
  #pragma unroll
  for (int m = 0; m < 2; ++m)
    #pragma unroll
    for (int j = 0; j < 4; ++j) {
      const int row = wr * 32 + m * 16 + fg * 4 + j;
      csh[row * 64 + wc * 32 + fr]      = acc[m][0][j] + bn0;
      csh[row * 64 + wc * 32 + 16 + fr] = acc[m][1][j] + bn1;
    }
  __syncthreads();
  #pragma unroll
  for (int i = 0; i < 4; ++i) {
    const int rl = i * 16 + (tid >> 4);
    const int gr = brow + rl;
    if (gr >= M_ROWS) continue;
    const int c4 = (tid & 15) * 4;
    float4 v = *(const float4*)&csh[rl * 64 + c4];
    if (ADD_RES) {
      float4 q = ld4(RES + (size_t)gr * 256 + bcol + c4);
      v.x += q.x; v.y += q.y; v.z += q.z; v.w += q.w;
    }
    if (OUT_MODE == 0) {
      *(float4*)&((float*)Cv)[(size_t)gr * N + bcol + c4] = v;
    } else if (OUT_MODE == 1) {
      ushort4 pk = make_ushort4(f2bf(v.x), f2bf(v.y), f2bf(v.z), f2bf(v.w));
      *(ushort4*)&((unsigned short*)Cv)[(size_t)gr * N + bcol + c4] = pk;
    } else {
      // head-split: vbuf2[head][row][32]
      const int head = (bcol + c4) >> 5;
      const int ch   = c4 & 31;
      ushort4 pk = make_ushort4(f2bf(v.x), f2bf(v.y), f2bf(v.z), f2bf(v.w));
      *(ushort4*)&((unsigned short*)Cv)[((size_t)head * M_ROWS + gr) * 32 + ch] = pk;
    }
  }
}

// ---- deformable sampling, head-partitioned for per-XCD L2 residency ----
// v: [8][M_ROWS][32] bf16 head-major; oa: [M][384] bf16 (off 0:256 | logits 256:384)
// Block = 64 queries x 1 head; head = blockIdx&7 -> XCD-affine under %8 round-robin.
__global__ __launch_bounds__(256) void msda5(
    const unsigned short* __restrict__ v, const unsigned short* __restrict__ oa,
    const float* __restrict__ ref, unsigned short* __restrict__ attout)
{
  constexpr int LW[4] = {100, 50, 25, 13};
  constexpr int LS[4] = {0, 10000, 12500, 13125};

  __shared__ int4   sidx[64][16];   // corner BYTE offsets into head slice
  __shared__ float4 swt [64][16];   // premultiplied weights

  const int bid   = blockIdx.x;
  const int h     = bid & 7;          // head == XCD
  const int chunk = bid >> 3;         // 0..415
  const int tid   = threadIdx.x;
  const int qi    = tid >> 2;         // query in block 0..63
  const int lq    = tid & 3;          // level (ph1) / channel-octet (ph2)
  const int bq    = chunk * 64 + qi;
  const bool active = bq < M_ROWS;
  const int b     = (bq >= NQ) ? 1 : 0;
  const int pmask = qi & 7;

  if (active) {
    const int l = lq;
    const int W = LW[l];
    const float fD = (float)W;
    const unsigned short* oarow = oa + (size_t)bq * 384;

    uint2 lg = *(const uint2*)(oarow + 256 + h * 16 + l * 4);
    float g0 = bfu_lo(lg.x), g1 = bfu_hi(lg.x), g2 = bfu_lo(lg.y), g3 = bfu_hi(lg.y);
    float mx = fmaxf(fmaxf(g0, g1), fmaxf(g2, g3));
    mx = fmaxf(mx, __shfl_xor(mx, 1));
    mx = fmaxf(mx, __shfl_xor(mx, 2));
    float e0 = __expf(g0-mx), e1 = __expf(g1-mx), e2 = __expf(g2-mx), e3 = __expf(g3-mx);
    float s = e0 + e1 + e2 + e3;
    s += __shfl_xor(s, 1);
    s += __shfl_xor(s, 2);
    const float inv = 1.f / s;
    const float ee[4] = {e0*inv, e1*inv, e2*inv, e3*inv};

    uint4 ov = *(const uint4*)(oarow + h * 32 + l * 8);
    const float oxy[8] = {bfu_lo(ov.x), bfu_hi(ov.x), bfu_lo(ov.y), bfu_hi(ov.y),
                          bfu_lo(ov.z), bfu_hi(ov.z), bfu_lo(ov.w), bfu_hi(ov.w)};
    const float rx = ref[(size_t)bq * 8 + l * 2];
    const float ry = ref[(size_t)bq * 8 + l * 2 + 1];
    const int rowbase = b * NV + LS[l];

    #pragma unroll
    for (int j = 0; j < 4; ++j) {
      const float x = (rx + oxy[2*j]   / fD) * fD - 0.5f;
      const float y = (ry + oxy[2*j+1] / fD) * fD - 0.5f;
      const float x0f = floorf(x), y0f = floorf(y);
      const float lx = x - x0f, ly = y - y0f;
      const int x0 = (int)x0f, y0 = (int)y0f;
      const int x1 = x0 + 1,  y1 = y0 + 1;
      const int cx0 = min(max(x0, 0), W - 1), cx1 = min(max(x1, 0), W - 1);
      const int cy0 = min(max(y0, 0), W - 1), cy1 = min(max(y1, 0), W - 1);
      const float f00 = (x0 >= 0 && x0 < W && y0 >= 0 && y0 < W) ? 1.f : 0.f;
      const float f10 = (x1 >= 0 && x1 < W && y0 >= 0 && y0 < W) ? 1.f : 0.f;
      const float f01 = (x0 >= 0 && x0 < W && y1 >= 0 && y1 < W) ? 1.f : 0.f;
      const float f11 = (x1 >= 0 && x1 < W && y1 >= 0 && y1 < W) ? 1.f : 0.f;
      const float wt = ee[j];
      const int pi = (l * 4 + j) ^ pmask;
      sidx[qi][pi] = make_int4((rowbase + cy0 * W + cx0) * 64,
                               (rowbase + cy0 * W + cx1) * 64,
                               (rowbase + cy1 * W + cx0) * 64,
                               (rowbase + cy1 * W + cx1) * 64);
      swt[qi][pi] = make_float4(wt * (1.f - lx) * (1.f - ly) * f00,
                                wt * lx * (1.f - ly) * f10,
                                wt * (1.f - lx) * ly * f01,
                                wt * lx * ly * f11);
    }
  }
  __syncthreads();

  if (active) {
    const char* vb = (const char*)v + (size_t)h * M_ROWS * 64 + lq * 16;
    float acc[8] = {0.f, 0.f, 0.f, 0.f, 0.f, 0.f, 0.f, 0.f};
    #pragma unroll
    for (int p = 0; p < 16; ++p) {
      const int4   ix = sidx[qi][p ^ pmask];
      const float4 w4 = swt[qi][p ^ pmask];
      uint4 c0 = *(const uint4*)(vb + ix.x);
      uint4 c1 = *(const uint4*)(vb + ix.y);
      uint4 c2 = *(const uint4*)(vb + ix.z);
      uint4 c3 = *(const uint4*)(vb + ix.w);
      acc[0] = fmaf(w4.x, bfu_lo(c0.x), acc[0]); acc[1] = fmaf(w4.x, bfu_hi(c0.x), acc[1]);
      acc[2] = fmaf(w4.x, bfu_lo(c0.y), acc[2]); acc[3] = fmaf(w4.x, bfu_hi(c0.y), acc[3]);
      acc[4] = fmaf(w4.x, bfu_lo(c0.z), acc[4]); acc[5] = fmaf(w4.x, bfu_hi(c0.z), acc[5]);
      acc[6] = fmaf(w4.x, bfu_lo(c0.w), acc[6]); acc[7] = fmaf(w4.x, bfu_hi(c0.w), acc[7]);
      acc[0] = fmaf(w4.y, bfu_lo(c1.x), acc[0]); acc[1] = fmaf(w4.y, bfu_hi(c1.x), acc[1]);
      acc[2] = fmaf(w4.y, bfu_lo(c1.y), acc[2]); acc[3] = fmaf(w4.y, bfu_hi(c1.y), acc[3]);
      acc[4] = fmaf(w4.y, bfu_lo(c1.z), acc[4]); acc[5] = fmaf(w4.y, bfu_hi(c1.z), acc[5]);
      acc[6] = fmaf(w4.y, bfu_lo(c1.w), acc[6]); acc[7] = fmaf(w4.y, bfu_hi(c1.w), acc[7]);
      acc[0] = fmaf(w4.z, bfu_lo(c2.x), acc[0]); acc[1] = fmaf(w4.z, bfu_hi(c2.x), acc[1]);
      acc[2] = fmaf(w4.z, bfu_lo(c2.y), acc[2]); acc[3] = fmaf(w4.z, bfu_hi(c2.y), acc[3]);
      acc[4] = fmaf(w4.z, bfu_lo(c2.z), acc[4]); acc[5] = fmaf(w4.z, bfu_hi(c2.z), acc[5]);
      acc[6] = fmaf(w4.z, bfu_lo(c2.w), acc[6]); acc[7] = fmaf(w4.z, bfu_hi(c2.w), acc[7]);
      acc[0] = fmaf(w4.w, bfu_lo(c3.x), acc[0]); acc[1] = fmaf(w4.w, bfu_hi(c3.x), acc[1]);
      acc[2] = fmaf(w4.w, bfu_lo(c3.y), acc[2]); acc[3] = fmaf(w4.w, bfu_hi(c3.y), acc[3]);
      acc[4] = fmaf(w4.w, bfu_lo(c3.z), acc[4]); acc[5] = fmaf(w4.w, bfu_hi(c3.z), acc[5]);
      acc[6] = fmaf(w4.w, bfu_lo(c3.w), acc[6]); acc[7] = fmaf(w4.w, bfu_hi(c3.w), acc[7]);
    }
    uint4 pk;
    pk.x = pk2(acc[0], acc[1]);
    pk.y = pk2(acc[2], acc[3]);
    pk.z = pk2(acc[4], acc[5]);
    pk.w = pk2(acc[6], acc[7]);
    *(uint4*)(attout + (size_t)bq * 256 + h * 32 + lq * 8) = pk;
  }
}

extern "C" void kernel_launch(void* const* d_in, const int* in_sizes, int n_in,
                              void* d_out, int out_size, void* d_ws, size_t ws_size,
                              hipStream_t stream) {
  const float* query  = (const float*)d_in[0];
  const float* value  = (const float*)d_in[2];
  const float* qpos   = (const float*)d_in[3];
  const float* refpts = (const float*)d_in[4];
  const float* W_value = (const float*)d_in[8];
  const float* b_value = (const float*)d_in[9];
  const float* W_off   = (const float*)d_in[10];
  const float* b_off   = (const float*)d_in[11];
  const float* W_attn  = (const float*)d_in[12];
  const float* b_attn  = (const float*)d_in[13];
  const float* W_out   = (const float*)d_in[14];
  const float* b_out   = (const float*)d_in[15];
  const float* W_ffn   = (const float*)d_in[16];
  const float* b_ffn   = (const float*)d_in[17];
  float* out = (float*)d_out;

  // workspace layout (~62 MB)
  unsigned short* oa    = (unsigned short*)d_ws;          // (MP,384) bf16
  unsigned short* vbuf2 = oa + (size_t)MP * 384;          // [8][M_ROWS][32] bf16
  unsigned short* AB1   = vbuf2 + (size_t)8 * M_ROWS * 32; // val_bf -> attout bf16
  unsigned short* AB2   = AB1 + (size_t)MP * 256;         // q_bf -> tmp bf16
  unsigned short* wts   = AB2 + (size_t)MP * 256;
  unsigned short* wv_t  = wts;
  unsigned short* woa_t = wts + 65536;   // [W_off^T ; W_attn^T]
  unsigned short* wu_t  = wts + 163840;
  unsigned short* wf_t  = wts + 229376;

  const dim3 blk(256);

  prep_all<<<dim3(2048), blk, 0, stream>>>(value, query, qpos, AB1, AB2,
      W_value, W_off, W_attn, W_out, W_ffn, wts);

  // v = value @ W_value + b -> vbuf2 head-split bf16
  gemm_gl<4,2,false><<<dim3(1664), blk, 0, stream>>>(
      AB1, wv_t, b_value, b_value, nullptr, vbuf2, 256);
  // [off | attn] = (q+pos) @ [W_off;W_attn] + biases -> bf16 (M,384)
  gemm_gl<6,1,false><<<dim3(2496), blk, 0, stream>>>(
      AB2, woa_t, b_off, b_attn, nullptr, oa, 384);
  // deformable sampling -> attout bf16 (overwrites AB1)
  msda5<<<dim3(8 * 416), blk, 0, stream>>>(vbuf2, oa, refpts, AB1);
  // tmp = attout @ W_out + b_out + query -> bf16 (overwrites AB2)
  gemm_gl<4,1,true><<<dim3(1664), blk, 0, stream>>>(
      AB1, wu_t, b_out, b_out, query, AB2, 256);
  // out = tmp @ W_ffn + b_ffn -> f32
  gemm_gl<4,0,false><<<dim3(1664), blk, 0, stream>>>(
      AB2, wf_t, b_ffn, b_ffn, nullptr, (void*)out, 256);
}